// Round 1
// baseline (797.951 us; speedup 1.0000x reference)
//
#include <hip/hip_runtime.h>
#include <hip/hip_bf16.h>

typedef unsigned long long u64;

#define WG        64
#define TILE      4096          // 64 threads * 64 items
#define RADIX     512
#define RBITS     9
#define NPASS     4
#define KSHIFT    21            // index bits in composite
#define KBIAS     (1LL << 21)   // min key is -1,787,119 > -2^21
#define KMASK     ((1u << 21) - 1)
#define GRP       128           // GROUP_SIZE

// meta (long long) layout at ws+64:
//  [0..8]  bsp (padded cumsum, NB+1 entries)
//  [9..16] winoff[b]  = bsp[b]-bs[b]
//  [17..24] tail[b]   = bsp[b+1]-G+r  (or INF if r==0)
//  [25] Np   [26] NB

__device__ __forceinline__ void hash3(long long x, long long y, long long z,
                                      long long boff, long long* v) {
  long long x1 = x >> 4, y1 = y >> 4, z1 = z >> 3;
  long long x2 = x & 15, y2 = y & 15, z2 = z & 7;
  long long sx  = 1 - 2*(x1 & 1), sy  = 1 - 2*(y1 & 1), sz  = 1 - 2*(z1 & 1);
  long long s2x = 1 - 2*(x2 & 1), s2y = 1 - 2*(y2 & 1), s2z = 1 - 2*(z2 & 1);
  // scaled consts: n1=m1=99, l1=27, n2=m2=48, l2=24
  v[0] = (99*y1 + 9801*z1 + sy*x1)*55296 + sy*(48*x2 + 2304*z2 + s2x*y2) + boff;
  v[1] = (99*z1 + 2673*x1 + sz*y1)*55296 + sz*(24*y2 + 1152*x2 + s2y*z2) + boff;
  v[2] = (27*x1 + 2673*y1 + sx*z1)*55296 + sx*(48*z2 + 1152*y2 + s2z*x2) + boff;
}

__global__ void count_k(const int* __restrict__ coords, unsigned* __restrict__ counts, int N) {
  __shared__ unsigned c[8];
  if (threadIdx.x < 8) c[threadIdx.x] = 0;
  __syncthreads();
  for (int i = blockIdx.x*blockDim.x + threadIdx.x; i < N; i += gridDim.x*blockDim.x)
    atomicAdd(&c[coords[4*i] & 7], 1u);
  __syncthreads();
  if (threadIdx.x < 8) atomicAdd(&counts[threadIdx.x], c[threadIdx.x]);
}

__global__ void prefix_k(const unsigned* __restrict__ counts, long long* __restrict__ meta,
                         const int* __restrict__ bsz) {
  int NB = *bsz; if (NB > 8) NB = 8;
  long long run_bs = 0, run_bsp = 0;
  meta[0] = 0;
  for (int b = 0; b < NB; b++) {
    long long c  = (long long)counts[b];
    long long cp = (c + GRP - 1) / GRP * GRP;
    long long r  = c % GRP;
    meta[9 + b]  = run_bsp - run_bs;
    meta[17 + b] = r ? (run_bsp + cp - GRP + r) : 0x7fffffffffffffffLL;
    run_bs += c; run_bsp += cp;
    meta[b + 1] = run_bsp;
  }
  meta[25] = run_bsp;
  meta[26] = NB;
}

__global__ void flat2win_k(const long long* __restrict__ meta, int* __restrict__ dout) {
  long long p = (long long)blockIdx.x * blockDim.x + threadIdx.x;
  long long Np = meta[25];
  if (p >= Np) return;
  int NB = (int)meta[26];
  int b = 0;
  while (b < NB - 1 && meta[b + 1] <= p) b++;
  long long pad = (p >= meta[17 + b]) ? 1 : 0;
  dout[p] = (int)(p - GRP * pad - meta[9 + b]);
}

__global__ void keygen_k(const int* __restrict__ coords, u64* __restrict__ keys,
                         const long long* __restrict__ meta, int* __restrict__ dout,
                         int N, int g0, int g, int doAux) {
  int i = blockIdx.x * blockDim.x + threadIdx.x;
  if (i >= N) return;
  int4 c4 = ((const int4*)coords)[i];
  long long b = c4.x;
  long long boff = b * 167772160LL;   // n*m*l*10
  long long v[6];
  hash3((long long)c4.y,     (long long)c4.z,     (long long)c4.w,     boff, v);
  hash3((long long)c4.y + 8, (long long)c4.z + 8, (long long)c4.w + 4, boff, v + 3);
  for (int s = g0; s < g0 + g; s++) {
    u64 comp = ((u64)(v[s] + KBIAS) << KSHIFT) | (unsigned)i;
    keys[(size_t)(s - g0) * N + i] = comp;
  }
  if (doAux) {
    long long Np = meta[25];
    dout[Np + i] = (int)(i + meta[9 + b]);
  }
}

__global__ void __launch_bounds__(WG) hist_k(const u64* __restrict__ keys, unsigned* __restrict__ hist,
                                             int N, int B, int shift) {
  __shared__ unsigned cnt[RADIX];
  int s = blockIdx.y, b = blockIdx.x, tid = threadIdx.x;
  for (int d = tid; d < RADIX; d += WG) cnt[d] = 0;
  __syncthreads();
  const u64* src = keys + (size_t)s * N;
  int chunk = b * TILE;
  #pragma unroll 4
  for (int t = 0; t < TILE / WG; t++) {
    int i = chunk + t * WG + tid;
    if (i < N) {
      unsigned d = (unsigned)(src[i] >> shift) & (RADIX - 1);
      atomicAdd(&cnt[d], 1u);
    }
  }
  __syncthreads();
  unsigned* h = hist + ((size_t)s * B + b) * RADIX;
  for (int d = tid; d < RADIX; d += WG) h[d] = cnt[d];
}

__global__ void __launch_bounds__(WG) scan_k(unsigned* __restrict__ hist, unsigned* __restrict__ total,
                                             int B) {
  int s = blockIdx.y;
  int d = blockIdx.x * WG + threadIdx.x;
  unsigned run = 0;
  int b = 0;
  for (; b + 16 <= B; b += 16) {
    unsigned v[16];
    #pragma unroll
    for (int j = 0; j < 16; j++) v[j] = hist[((size_t)s * B + b + j) * RADIX + d];
    #pragma unroll
    for (int j = 0; j < 16; j++) { hist[((size_t)s * B + b + j) * RADIX + d] = run; run += v[j]; }
  }
  for (; b < B; b++) {
    size_t idx = ((size_t)s * B + b) * RADIX + d;
    unsigned v = hist[idx]; hist[idx] = run; run += v;
  }
  total[(size_t)s * RADIX + d] = run;
}

__global__ void __launch_bounds__(WG) base_k(const unsigned* __restrict__ total,
                                             unsigned* __restrict__ dbase) {
  int s = blockIdx.x, lane = threadIdx.x;
  unsigned run = 0;
  for (int c = 0; c < RADIX / WG; c++) {
    unsigned v = total[(size_t)s * RADIX + c * WG + lane];
    unsigned x = v;
    for (int off = 1; off < WG; off <<= 1) {
      unsigned u = __shfl_up(x, off);
      if (lane >= off) x += u;
    }
    dbase[(size_t)s * RADIX + c * WG + lane] = run + x - v;
    run += __shfl(x, WG - 1);
  }
}

__global__ void __launch_bounds__(WG) scatter_k(const u64* __restrict__ src, u64* __restrict__ dst,
                                                const unsigned* __restrict__ hist,
                                                const unsigned* __restrict__ dbase,
                                                int N, int B, int shift, int finalPass,
                                                int* __restrict__ dout,
                                                const long long* __restrict__ meta, int g0) {
  __shared__ unsigned offs[RADIX];
  int s = blockIdx.y, b = blockIdx.x, lane = threadIdx.x;
  const unsigned* hrow = hist + ((size_t)s * B + b) * RADIX;
  const unsigned* brow = dbase + (size_t)s * RADIX;
  for (int d = lane; d < RADIX; d += WG) offs[d] = hrow[d] + brow[d];
  __syncthreads();
  const u64* in = src + (size_t)s * N;
  u64* out = dst + (size_t)s * N;
  long long obase = 0;
  if (finalPass) obase = meta[25] + (long long)N * (1 + g0 + s);
  int chunk = b * TILE;
  u64 lanemask_lt = (1ULL << lane) - 1;
  for (int t = 0; t < TILE / WG; t++) {
    int i = chunk + t * WG + lane;
    if (i < N) {
      u64 k = in[i];
      unsigned d = (unsigned)(k >> shift) & (RADIX - 1);
      u64 m = __ballot(1);                       // active-lane mask
      #pragma unroll
      for (int bit = 0; bit < RBITS; bit++) {
        u64 bal = __ballot((d >> bit) & 1);
        m &= ((d >> bit) & 1) ? bal : ~bal;
      }
      u64 below = m & lanemask_lt;
      unsigned rank = (unsigned)__popcll(below);
      unsigned pbase = offs[d];                   // all lanes read first (lockstep)
      unsigned pos = pbase + rank;
      if (below == 0) offs[d] = pbase + (unsigned)__popcll(m);  // leader updates after
      if (finalPass) dout[obase + pos] = (int)(k & KMASK);
      else           out[pos] = k;
    }
  }
}

extern "C" void kernel_launch(void* const* d_in, const int* in_sizes, int n_in,
                              void* d_out, int out_size, void* d_ws, size_t ws_size,
                              hipStream_t stream) {
  const int* coords = (const int*)d_in[0];
  const int* bsz    = (const int*)d_in[1];
  int N = in_sizes[0] / 4;
  int* dout = (int*)d_out;
  char* ws = (char*)d_ws;
  int B = (N + TILE - 1) / TILE;

  auto align256 = [](size_t x) { return (x + 255) & ~(size_t)255; };

  // choose how many sorts to batch per group based on ws_size
  int g = 1;
  size_t offHist = 512, offTotal = 0, offBase = 0, offA = 0, offB = 0;
  const int cands[4] = {6, 3, 2, 1};
  for (int ci = 0; ci < 4; ci++) {
    int cg = cands[ci];
    size_t histB = (size_t)cg * B * RADIX * 4;
    size_t oT = offHist + histB;
    size_t oBs = oT + (size_t)cg * RADIX * 4;
    size_t oA = align256(oBs + (size_t)cg * RADIX * 4);
    size_t oB = oA + (size_t)cg * N * 8;
    size_t need = oB + (size_t)cg * N * 8;
    if (need <= ws_size || cg == 1) {
      g = cg; offTotal = oT; offBase = oBs; offA = oA; offB = oB;
      if (need <= ws_size) break;
    }
  }

  unsigned*  counts = (unsigned*)ws;
  long long* meta   = (long long*)(ws + 64);
  unsigned*  hist   = (unsigned*)(ws + offHist);
  unsigned*  total  = (unsigned*)(ws + offTotal);
  unsigned*  dbase  = (unsigned*)(ws + offBase);
  u64*       keysA  = (u64*)(ws + offA);
  u64*       keysB  = (u64*)(ws + offB);

  hipMemsetAsync(ws, 0, 512, stream);
  count_k<<<1024, 256, 0, stream>>>(coords, counts, N);
  prefix_k<<<1, 1, 0, stream>>>(counts, meta, bsz);
  flat2win_k<<<(N + 8 * GRP + 255) / 256, 256, 0, stream>>>(meta, dout);

  for (int g0 = 0; g0 < 6; g0 += g) {
    keygen_k<<<(N + 255) / 256, 256, 0, stream>>>(coords, keysA, meta, dout, N, g0, g, g0 == 0);
    u64* src = keysA; u64* dst = keysB;
    for (int p = 0; p < NPASS; p++) {
      int shift = KSHIFT + RBITS * p;
      int fin = (p == NPASS - 1);
      hist_k<<<dim3(B, g), WG, 0, stream>>>(src, hist, N, B, shift);
      scan_k<<<dim3(RADIX / WG, g), WG, 0, stream>>>(hist, total, B);
      base_k<<<g, WG, 0, stream>>>(total, dbase);
      scatter_k<<<dim3(B, g), WG, 0, stream>>>(src, dst, hist, dbase, N, B, shift, fin,
                                               dout, meta, g0);
      u64* tmp = src; src = dst; dst = tmp;
    }
  }
}

// Round 2
// 764.588 us; speedup vs baseline: 1.0436x; 1.0436x over previous
//
#include <hip/hip_runtime.h>
#include <hip/hip_bf16.h>

typedef unsigned long long u64;

#define BLOCK     256           // 4 waves per block
#define WAVES     4
#define TILE      16384         // items per histogram/scatter block
#define SUBT      4096          // items per wave (contiguous, for stability)
#define CHUNKS    (SUBT / 64)   // 64 chunks of 64 items per wave
#define RADIX     512
#define RBITS     9
#define NPASS     4
#define KSHIFT    21            // index bits in composite
#define KBIAS     (1LL << 21)   // min key is -1,787,119 > -2^21
#define KMASK     ((1u << 21) - 1)
#define GRP       128           // GROUP_SIZE

// meta (long long) layout at ws+64:
//  [0..8]  bsp (padded cumsum, NB+1 entries)
//  [9..16] winoff[b]  = bsp[b]-bs[b]
//  [17..24] tail[b]   = bsp[b+1]-G+r  (or INF if r==0)
//  [25] Np   [26] NB

__device__ __forceinline__ void hash3(long long x, long long y, long long z,
                                      long long boff, long long* v) {
  long long x1 = x >> 4, y1 = y >> 4, z1 = z >> 3;
  long long x2 = x & 15, y2 = y & 15, z2 = z & 7;
  long long sx  = 1 - 2*(x1 & 1), sy  = 1 - 2*(y1 & 1), sz  = 1 - 2*(z1 & 1);
  long long s2x = 1 - 2*(x2 & 1), s2y = 1 - 2*(y2 & 1), s2z = 1 - 2*(z2 & 1);
  // scaled consts: n1=m1=99, l1=27, n2=m2=48, l2=24
  v[0] = (99*y1 + 9801*z1 + sy*x1)*55296 + sy*(48*x2 + 2304*z2 + s2x*y2) + boff;
  v[1] = (99*z1 + 2673*x1 + sz*y1)*55296 + sz*(24*y2 + 1152*x2 + s2y*z2) + boff;
  v[2] = (27*x1 + 2673*y1 + sx*z1)*55296 + sx*(48*z2 + 1152*y2 + s2z*x2) + boff;
}

__global__ void count_k(const int* __restrict__ coords, unsigned* __restrict__ counts, int N) {
  __shared__ unsigned c[8];
  if (threadIdx.x < 8) c[threadIdx.x] = 0;
  __syncthreads();
  for (int i = blockIdx.x*blockDim.x + threadIdx.x; i < N; i += gridDim.x*blockDim.x)
    atomicAdd(&c[coords[4*i] & 7], 1u);
  __syncthreads();
  if (threadIdx.x < 8) atomicAdd(&counts[threadIdx.x], c[threadIdx.x]);
}

__global__ void prefix_k(const unsigned* __restrict__ counts, long long* __restrict__ meta,
                         const int* __restrict__ bsz) {
  int NB = *bsz; if (NB > 8) NB = 8;
  long long run_bs = 0, run_bsp = 0;
  meta[0] = 0;
  for (int b = 0; b < NB; b++) {
    long long c  = (long long)counts[b];
    long long cp = (c + GRP - 1) / GRP * GRP;
    long long r  = c % GRP;
    meta[9 + b]  = run_bsp - run_bs;
    meta[17 + b] = r ? (run_bsp + cp - GRP + r) : 0x7fffffffffffffffLL;
    run_bs += c; run_bsp += cp;
    meta[b + 1] = run_bsp;
  }
  meta[25] = run_bsp;
  meta[26] = NB;
}

__global__ void flat2win_k(const long long* __restrict__ meta, int* __restrict__ dout) {
  long long p = (long long)blockIdx.x * blockDim.x + threadIdx.x;
  long long Np = meta[25];
  if (p >= Np) return;
  int NB = (int)meta[26];
  int b = 0;
  while (b < NB - 1 && meta[b + 1] <= p) b++;
  long long pad = (p >= meta[17 + b]) ? 1 : 0;
  dout[p] = (int)(p - GRP * pad - meta[9 + b]);
}

__global__ void keygen_k(const int* __restrict__ coords, u64* __restrict__ keys,
                         const long long* __restrict__ meta, int* __restrict__ dout,
                         int N, int g0, int g, int doAux) {
  int i = blockIdx.x * blockDim.x + threadIdx.x;
  if (i >= N) return;
  int4 c4 = ((const int4*)coords)[i];
  long long b = c4.x;
  long long boff = b * 167772160LL;   // n*m*l*10
  long long v[6];
  hash3((long long)c4.y,     (long long)c4.z,     (long long)c4.w,     boff, v);
  hash3((long long)c4.y + 8, (long long)c4.z + 8, (long long)c4.w + 4, boff, v + 3);
  for (int s = g0; s < g0 + g; s++) {
    u64 comp = ((u64)(v[s] + KBIAS) << KSHIFT) | (unsigned)i;
    keys[(size_t)(s - g0) * N + i] = comp;
  }
  if (doAux) {
    long long Np = meta[25];
    dout[Np + i] = (int)(i + meta[9 + b]);
  }
}

// histogram: per-block totals AND per-wave sub-histograms (wave w counts
// exactly sub-tile w, so scatter can reuse them for cross-wave prefixes)
__global__ void __launch_bounds__(BLOCK) hist_k(const u64* __restrict__ keys,
                                                unsigned* __restrict__ hist,
                                                unsigned* __restrict__ whist,
                                                int N, int B, int shift) {
  __shared__ unsigned cnt[WAVES][RADIX];
  int s = blockIdx.y, b = blockIdx.x, tid = threadIdx.x;
  int wave = tid >> 6, lane = tid & 63;
  for (int j = tid; j < WAVES * RADIX; j += BLOCK) ((unsigned*)cnt)[j] = 0;
  __syncthreads();
  const u64* src = keys + (size_t)s * N;
  int subbase = b * TILE + wave * SUBT;
  #pragma unroll 4
  for (int t = 0; t < CHUNKS; t++) {
    int i = subbase + t * 64 + lane;
    if (i < N) {
      unsigned d = (unsigned)(src[i] >> shift) & (RADIX - 1);
      atomicAdd(&cnt[wave][d], 1u);
    }
  }
  __syncthreads();
  size_t wb = (size_t)(s * B + b) * (WAVES * RADIX);
  for (int j = tid; j < WAVES * RADIX; j += BLOCK) whist[wb + j] = ((unsigned*)cnt)[j];
  unsigned* h = hist + (size_t)(s * B + b) * RADIX;
  for (int d = tid; d < RADIX; d += BLOCK)
    h[d] = cnt[0][d] + cnt[1][d] + cnt[2][d] + cnt[3][d];
}

__global__ void __launch_bounds__(64) scan_k(unsigned* __restrict__ hist, unsigned* __restrict__ total,
                                             int B) {
  int s = blockIdx.y;
  int d = blockIdx.x * 64 + threadIdx.x;
  unsigned run = 0;
  int b = 0;
  for (; b + 16 <= B; b += 16) {
    unsigned v[16];
    #pragma unroll
    for (int j = 0; j < 16; j++) v[j] = hist[((size_t)s * B + b + j) * RADIX + d];
    #pragma unroll
    for (int j = 0; j < 16; j++) { hist[((size_t)s * B + b + j) * RADIX + d] = run; run += v[j]; }
  }
  for (; b < B; b++) {
    size_t idx = ((size_t)s * B + b) * RADIX + d;
    unsigned v = hist[idx]; hist[idx] = run; run += v;
  }
  total[(size_t)s * RADIX + d] = run;
}

__global__ void __launch_bounds__(64) base_k(const unsigned* __restrict__ total,
                                             unsigned* __restrict__ dbase) {
  int s = blockIdx.x, lane = threadIdx.x;
  unsigned run = 0;
  for (int c = 0; c < RADIX / 64; c++) {
    unsigned v = total[(size_t)s * RADIX + c * 64 + lane];
    unsigned x = v;
    for (int off = 1; off < 64; off <<= 1) {
      unsigned u = __shfl_up(x, off);
      if (lane >= off) x += u;
    }
    dbase[(size_t)s * RADIX + c * 64 + lane] = run + x - v;
    run += __shfl(x, 63);
  }
}

__global__ void __launch_bounds__(BLOCK) scatter_k(const u64* __restrict__ src, u64* __restrict__ dst,
                                                   const unsigned* __restrict__ hist,
                                                   const unsigned* __restrict__ whist,
                                                   const unsigned* __restrict__ dbase,
                                                   int N, int B, int shift, int finalPass,
                                                   int* __restrict__ dout,
                                                   const long long* __restrict__ meta, int g0) {
  __shared__ unsigned cnt[WAVES][RADIX];
  int s = blockIdx.y, b = blockIdx.x, tid = threadIdx.x;
  int wave = tid >> 6, lane = tid & 63;

  // load per-wave sub-histograms (counted by hist_k with identical sub-tiling)
  size_t wb = (size_t)(s * B + b) * (WAVES * RADIX);
  for (int j = tid; j < WAVES * RADIX; j += BLOCK) ((unsigned*)cnt)[j] = whist[wb + j];
  __syncthreads();

  // seed: cnt[w][d] = global base + exclusive cross-wave prefix
  const unsigned* hrow = hist + (size_t)(s * B + b) * RADIX;
  const unsigned* brow = dbase + (size_t)s * RADIX;
  for (int d = tid; d < RADIX; d += BLOCK) {
    unsigned b0 = hrow[d] + brow[d];
    unsigned c0 = cnt[0][d], c1 = cnt[1][d], c2 = cnt[2][d];
    cnt[0][d] = b0;
    cnt[1][d] = b0 + c0;
    cnt[2][d] = b0 + c0 + c1;
    cnt[3][d] = b0 + c0 + c1 + c2;
  }
  __syncthreads();

  const u64* in = src + (size_t)s * N;
  u64* out = dst + (size_t)s * N;
  long long obase = 0;
  if (finalPass) obase = meta[25] + (long long)N * (1 + g0 + s);

  int subbase = b * TILE + wave * SUBT;
  if (subbase >= N) return;          // tail wave with no work (no barriers after)
  unsigned* row = cnt[wave];
  u64 lanemask_lt = (1ULL << lane) - 1;
  int i = subbase + lane;
  u64 k = in[min(i, N - 1)];          // prefetched chunk 0
  for (int t = 0; t < CHUNKS; t++) {
    bool valid = (i < N);
    u64 kc = k;
    int inext = i + 64;
    if (t + 1 < CHUNKS) k = in[min(inext, N - 1)];   // prefetch next chunk
    unsigned d = (unsigned)(kc >> shift) & (RADIX - 1);
    u64 m = __ballot(valid);
    #pragma unroll
    for (int bit = 0; bit < RBITS; bit++) {
      u64 bal = __ballot(valid && ((d >> bit) & 1));
      m &= ((d >> bit) & 1) ? bal : ~bal;
    }
    u64 below = m & lanemask_lt;
    unsigned rank = (unsigned)__popcll(below);
    unsigned pbase = row[d];                       // all lanes read first (lockstep)
    unsigned pos = pbase + rank;
    if (valid && below == 0) row[d] = pbase + (unsigned)__popcll(m);  // leader updates after
    if (valid) {
      if (finalPass) dout[obase + pos] = (int)(kc & KMASK);
      else           out[pos] = kc;
    }
    i = inext;
  }
}

extern "C" void kernel_launch(void* const* d_in, const int* in_sizes, int n_in,
                              void* d_out, int out_size, void* d_ws, size_t ws_size,
                              hipStream_t stream) {
  const int* coords = (const int*)d_in[0];
  const int* bsz    = (const int*)d_in[1];
  int N = in_sizes[0] / 4;
  int* dout = (int*)d_out;
  char* ws = (char*)d_ws;
  int B = (N + TILE - 1) / TILE;

  auto align256 = [](size_t x) { return (x + 255) & ~(size_t)255; };

  // choose how many sorts to batch per group based on ws_size
  int g = 1;
  size_t offHist = 512, offWhist = 0, offTotal = 0, offBase = 0, offA = 0, offB = 0;
  const int cands[4] = {6, 3, 2, 1};
  for (int ci = 0; ci < 4; ci++) {
    int cg = cands[ci];
    size_t oW = offHist + (size_t)cg * B * RADIX * 4;
    size_t oT = oW + (size_t)cg * B * WAVES * RADIX * 4;
    size_t oBs = oT + (size_t)cg * RADIX * 4;
    size_t oA = align256(oBs + (size_t)cg * RADIX * 4);
    size_t oB = oA + (size_t)cg * N * 8;
    size_t need = oB + (size_t)cg * N * 8;
    if (need <= ws_size || cg == 1) {
      g = cg; offWhist = oW; offTotal = oT; offBase = oBs; offA = oA; offB = oB;
      if (need <= ws_size) break;
    }
  }

  unsigned*  counts = (unsigned*)ws;
  long long* meta   = (long long*)(ws + 64);
  unsigned*  hist   = (unsigned*)(ws + offHist);
  unsigned*  whist  = (unsigned*)(ws + offWhist);
  unsigned*  total  = (unsigned*)(ws + offTotal);
  unsigned*  dbase  = (unsigned*)(ws + offBase);
  u64*       keysA  = (u64*)(ws + offA);
  u64*       keysB  = (u64*)(ws + offB);

  hipMemsetAsync(ws, 0, 512, stream);
  count_k<<<1024, 256, 0, stream>>>(coords, counts, N);
  prefix_k<<<1, 1, 0, stream>>>(counts, meta, bsz);
  flat2win_k<<<(N + 8 * GRP + 255) / 256, 256, 0, stream>>>(meta, dout);

  for (int g0 = 0; g0 < 6; g0 += g) {
    keygen_k<<<(N + 255) / 256, 256, 0, stream>>>(coords, keysA, meta, dout, N, g0, g, g0 == 0);
    u64* src = keysA; u64* dst = keysB;
    for (int p = 0; p < NPASS; p++) {
      int shift = KSHIFT + RBITS * p;
      int fin = (p == NPASS - 1);
      hist_k<<<dim3(B, g), BLOCK, 0, stream>>>(src, hist, whist, N, B, shift);
      scan_k<<<dim3(RADIX / 64, g), 64, 0, stream>>>(hist, total, B);
      base_k<<<g, 64, 0, stream>>>(total, dbase);
      scatter_k<<<dim3(B, g), BLOCK, 0, stream>>>(src, dst, hist, whist, dbase, N, B, shift, fin,
                                                  dout, meta, g0);
      u64* tmp = src; src = dst; dst = tmp;
    }
  }
}

// Round 3
// 506.156 us; speedup vs baseline: 1.5765x; 1.5106x over previous
//
#include <hip/hip_runtime.h>
#include <hip/hip_bf16.h>

typedef unsigned long long u64;

#define BLOCK     256           // 4 waves per block
#define WAVES     4
#define TILE      4096          // items per histogram/scatter block
#define SUBT      1024          // items per wave (contiguous, for stability)
#define CHUNKS    (SUBT / 64)   // chunks of 64 items per wave
#define RADIX     512
#define RBITS     9
#define NPASS     4
#define KSHIFT    21            // index bits in composite
#define KBIAS     (1LL << 21)   // min key is -1,787,119 > -2^21
#define KMASK     ((1u << 21) - 1)
#define GRP       128           // GROUP_SIZE

// meta (long long) layout at ws+64:
//  [0..8]  bsp (padded cumsum, NB+1 entries)
//  [9..16] winoff[b]  = bsp[b]-bs[b]
//  [17..24] tail[b]   = bsp[b+1]-G+r  (or INF if r==0)
//  [25] Np   [26] NB

__device__ __forceinline__ void hash3(long long x, long long y, long long z,
                                      long long boff, long long* v) {
  long long x1 = x >> 4, y1 = y >> 4, z1 = z >> 3;
  long long x2 = x & 15, y2 = y & 15, z2 = z & 7;
  long long sx  = 1 - 2*(x1 & 1), sy  = 1 - 2*(y1 & 1), sz  = 1 - 2*(z1 & 1);
  long long s2x = 1 - 2*(x2 & 1), s2y = 1 - 2*(y2 & 1), s2z = 1 - 2*(z2 & 1);
  // scaled consts: n1=m1=99, l1=27, n2=m2=48, l2=24
  v[0] = (99*y1 + 9801*z1 + sy*x1)*55296 + sy*(48*x2 + 2304*z2 + s2x*y2) + boff;
  v[1] = (99*z1 + 2673*x1 + sz*y1)*55296 + sz*(24*y2 + 1152*x2 + s2y*z2) + boff;
  v[2] = (27*x1 + 2673*y1 + sx*z1)*55296 + sx*(48*z2 + 1152*y2 + s2z*x2) + boff;
}

__global__ void count_k(const int* __restrict__ coords, unsigned* __restrict__ counts, int N) {
  __shared__ unsigned c[8];
  if (threadIdx.x < 8) c[threadIdx.x] = 0;
  __syncthreads();
  for (int i = blockIdx.x*blockDim.x + threadIdx.x; i < N; i += gridDim.x*blockDim.x)
    atomicAdd(&c[coords[4*i] & 7], 1u);
  __syncthreads();
  if (threadIdx.x < 8) atomicAdd(&counts[threadIdx.x], c[threadIdx.x]);
}

__global__ void prefix_k(const unsigned* __restrict__ counts, long long* __restrict__ meta,
                         const int* __restrict__ bsz) {
  int NB = *bsz; if (NB > 8) NB = 8;
  long long run_bs = 0, run_bsp = 0;
  meta[0] = 0;
  for (int b = 0; b < NB; b++) {
    long long c  = (long long)counts[b];
    long long cp = (c + GRP - 1) / GRP * GRP;
    long long r  = c % GRP;
    meta[9 + b]  = run_bsp - run_bs;
    meta[17 + b] = r ? (run_bsp + cp - GRP + r) : 0x7fffffffffffffffLL;
    run_bs += c; run_bsp += cp;
    meta[b + 1] = run_bsp;
  }
  meta[25] = run_bsp;
  meta[26] = NB;
}

__global__ void flat2win_k(const long long* __restrict__ meta, int* __restrict__ dout) {
  long long p = (long long)blockIdx.x * blockDim.x + threadIdx.x;
  long long Np = meta[25];
  if (p >= Np) return;
  int NB = (int)meta[26];
  int b = 0;
  while (b < NB - 1 && meta[b + 1] <= p) b++;
  long long pad = (p >= meta[17 + b]) ? 1 : 0;
  dout[p] = (int)(p - GRP * pad - meta[9 + b]);
}

__global__ void keygen_k(const int* __restrict__ coords, u64* __restrict__ keys,
                         const long long* __restrict__ meta, int* __restrict__ dout,
                         int N, int g0, int g, int doAux) {
  int i = blockIdx.x * blockDim.x + threadIdx.x;
  if (i >= N) return;
  int4 c4 = ((const int4*)coords)[i];
  long long b = c4.x;
  long long boff = b * 167772160LL;   // n*m*l*10
  long long v[6];
  hash3((long long)c4.y,     (long long)c4.z,     (long long)c4.w,     boff, v);
  hash3((long long)c4.y + 8, (long long)c4.z + 8, (long long)c4.w + 4, boff, v + 3);
  for (int s = g0; s < g0 + g; s++) {
    u64 comp = ((u64)(v[s] + KBIAS) << KSHIFT) | (unsigned)i;
    keys[(size_t)(s - g0) * N + i] = comp;
  }
  if (doAux) {
    long long Np = meta[25];
    dout[Np + i] = (int)(i + meta[9 + b]);
  }
}

// histogram: per-block totals AND per-wave sub-histograms (wave w counts
// exactly sub-tile w, so scatter can reuse them for local prefixes)
__global__ void __launch_bounds__(BLOCK) hist_k(const u64* __restrict__ keys,
                                                unsigned* __restrict__ hist,
                                                unsigned* __restrict__ whist,
                                                int N, int B, int shift) {
  __shared__ unsigned cnt[WAVES][RADIX];
  int s = blockIdx.y, b = blockIdx.x, tid = threadIdx.x;
  int wave = tid >> 6, lane = tid & 63;
  for (int j = tid; j < WAVES * RADIX; j += BLOCK) ((unsigned*)cnt)[j] = 0;
  __syncthreads();
  const u64* src = keys + (size_t)s * N;
  int subbase = b * TILE + wave * SUBT;
  #pragma unroll 4
  for (int t = 0; t < CHUNKS; t++) {
    int i = subbase + t * 64 + lane;
    if (i < N) {
      unsigned d = (unsigned)(src[i] >> shift) & (RADIX - 1);
      atomicAdd(&cnt[wave][d], 1u);
    }
  }
  __syncthreads();
  size_t wb = (size_t)(s * B + b) * (WAVES * RADIX);
  for (int j = tid; j < WAVES * RADIX; j += BLOCK) whist[wb + j] = ((unsigned*)cnt)[j];
  unsigned* h = hist + (size_t)(s * B + b) * RADIX;
  for (int d = tid; d < RADIX; d += BLOCK)
    h[d] = cnt[0][d] + cnt[1][d] + cnt[2][d] + cnt[3][d];
}

__global__ void __launch_bounds__(64) scan_k(unsigned* __restrict__ hist, unsigned* __restrict__ total,
                                             int B) {
  int s = blockIdx.y;
  int d = blockIdx.x * 64 + threadIdx.x;
  unsigned run = 0;
  int b = 0;
  for (; b + 16 <= B; b += 16) {
    unsigned v[16];
    #pragma unroll
    for (int j = 0; j < 16; j++) v[j] = hist[((size_t)s * B + b + j) * RADIX + d];
    #pragma unroll
    for (int j = 0; j < 16; j++) { hist[((size_t)s * B + b + j) * RADIX + d] = run; run += v[j]; }
  }
  for (; b < B; b++) {
    size_t idx = ((size_t)s * B + b) * RADIX + d;
    unsigned v = hist[idx]; hist[idx] = run; run += v;
  }
  total[(size_t)s * RADIX + d] = run;
}

__global__ void __launch_bounds__(64) base_k(const unsigned* __restrict__ total,
                                             unsigned* __restrict__ dbase) {
  int s = blockIdx.x, lane = threadIdx.x;
  unsigned run = 0;
  for (int c = 0; c < RADIX / 64; c++) {
    unsigned v = total[(size_t)s * RADIX + c * 64 + lane];
    unsigned x = v;
    for (int off = 1; off < 64; off <<= 1) {
      unsigned u = __shfl_up(x, off);
      if (lane >= off) x += u;
    }
    dbase[(size_t)s * RADIX + c * 64 + lane] = run + x - v;
    run += __shfl(x, 63);
  }
}

// LDS-staged scatter: rank into local digit-sorted order in LDS, then
// stream out with coalesced writes (fixes the 4x partial-sector writeback).
__global__ void __launch_bounds__(BLOCK) scatter_k(const u64* __restrict__ src, u64* __restrict__ dst,
                                                   const unsigned* __restrict__ hist,
                                                   const unsigned* __restrict__ whist,
                                                   const unsigned* __restrict__ dbase,
                                                   int N, int B, int shift, int finalPass,
                                                   int* __restrict__ dout,
                                                   const long long* __restrict__ meta, int g0) {
  __shared__ u64 items[TILE];                 // 32 KB
  __shared__ unsigned short cnt[WAVES][RADIX];// 4 KB  per-wave running local counters
  __shared__ int ex[RADIX];                   // 2 KB  local exclusive digit scan
  __shared__ int fix[RADIX];                  // 2 KB  global_base - local_base per digit
  int s = blockIdx.y, b = blockIdx.x, tid = threadIdx.x;
  int wave = tid >> 6, lane = tid & 63;

  // per-wave sub-histograms (counted by hist_k with identical sub-tiling)
  size_t wb = (size_t)(s * B + b) * (WAVES * RADIX);
  for (int d = tid; d < RADIX; d += BLOCK) {
    unsigned c0 = whist[wb + 0 * RADIX + d];
    unsigned c1 = whist[wb + 1 * RADIX + d];
    unsigned c2 = whist[wb + 2 * RADIX + d];
    unsigned c3 = whist[wb + 3 * RADIX + d];
    cnt[0][d] = 0;
    cnt[1][d] = (unsigned short)c0;
    cnt[2][d] = (unsigned short)(c0 + c1);
    cnt[3][d] = (unsigned short)(c0 + c1 + c2);
    ex[d] = (int)(c0 + c1 + c2 + c3);        // block total, scanned below
  }
  __syncthreads();
  if (wave == 0) {                            // exclusive scan of 512 totals
    int run = 0;
    #pragma unroll
    for (int c = 0; c < RADIX / 64; c++) {
      int v = ex[c * 64 + lane];
      int x = v;
      for (int off = 1; off < 64; off <<= 1) {
        int u = __shfl_up(x, off);
        if (lane >= off) x += u;
      }
      ex[c * 64 + lane] = run + x - v;
      run += __shfl(x, 63);
    }
  }
  __syncthreads();
  const unsigned* hrow = hist + (size_t)(s * B + b) * RADIX;
  const unsigned* brow = dbase + (size_t)s * RADIX;
  for (int d = tid; d < RADIX; d += BLOCK) {
    int e = ex[d];
    fix[d] = (int)(hrow[d] + brow[d]) - e;    // global addr = fix[d] + local slot
    cnt[0][d] = (unsigned short)(cnt[0][d] + e);
    cnt[1][d] = (unsigned short)(cnt[1][d] + e);
    cnt[2][d] = (unsigned short)(cnt[2][d] + e);
    cnt[3][d] = (unsigned short)(cnt[3][d] + e);
  }
  __syncthreads();

  // ranking phase: wave-lockstep ballot-match, write keys to LDS local slot
  const u64* in = src + (size_t)s * N;
  int subbase = b * TILE + wave * SUBT;
  unsigned short* row = cnt[wave];
  u64 lanemask_lt = (1ULL << lane) - 1;
  int i = subbase + lane;
  u64 k = in[min(i, N - 1)];                  // prefetched chunk 0
  for (int t = 0; t < CHUNKS; t++) {
    bool valid = (i < N);
    u64 kc = k;
    int inext = i + 64;
    if (t + 1 < CHUNKS) k = in[min(inext, N - 1)];   // prefetch next chunk
    unsigned d = (unsigned)(kc >> shift) & (RADIX - 1);
    u64 m = __ballot(valid);
    #pragma unroll
    for (int bit = 0; bit < RBITS; bit++) {
      u64 bal = __ballot(valid && ((d >> bit) & 1));
      m &= ((d >> bit) & 1) ? bal : ~bal;
    }
    u64 below = m & lanemask_lt;
    unsigned rank = (unsigned)__popcll(below);
    unsigned pbase = row[d];                  // all lanes read first (lockstep)
    unsigned pos = pbase + rank;
    if (valid && below == 0) row[d] = (unsigned short)(pbase + (unsigned)__popcll(m));
    if (valid) items[pos] = kc;
    i = inext;
  }
  __syncthreads();

  // write-out: linear LDS read -> coalesced global stores
  u64* out = dst + (size_t)s * N;
  long long obase = 0;
  if (finalPass) obase = meta[25] + (long long)N * (1 + g0 + s);
  int validCount = N - b * TILE; if (validCount > TILE) validCount = TILE;
  #pragma unroll 4
  for (int t = 0; t < TILE / BLOCK; t++) {
    int j = t * BLOCK + tid;
    if (j < validCount) {
      u64 kc = items[j];
      unsigned d = (unsigned)(kc >> shift) & (RADIX - 1);
      int pos = fix[d] + j;
      if (finalPass) dout[obase + pos] = (int)(kc & KMASK);
      else           out[pos] = kc;
    }
  }
}

extern "C" void kernel_launch(void* const* d_in, const int* in_sizes, int n_in,
                              void* d_out, int out_size, void* d_ws, size_t ws_size,
                              hipStream_t stream) {
  const int* coords = (const int*)d_in[0];
  const int* bsz    = (const int*)d_in[1];
  int N = in_sizes[0] / 4;
  int* dout = (int*)d_out;
  char* ws = (char*)d_ws;
  int B = (N + TILE - 1) / TILE;

  auto align256 = [](size_t x) { return (x + 255) & ~(size_t)255; };

  // choose how many sorts to batch per group based on ws_size
  int g = 1;
  size_t offHist = 512, offWhist = 0, offTotal = 0, offBase = 0, offA = 0, offB = 0;
  const int cands[4] = {6, 3, 2, 1};
  for (int ci = 0; ci < 4; ci++) {
    int cg = cands[ci];
    size_t oW = offHist + (size_t)cg * B * RADIX * 4;
    size_t oT = oW + (size_t)cg * B * WAVES * RADIX * 4;
    size_t oBs = oT + (size_t)cg * RADIX * 4;
    size_t oA = align256(oBs + (size_t)cg * RADIX * 4);
    size_t oB = oA + (size_t)cg * N * 8;
    size_t need = oB + (size_t)cg * N * 8;
    if (need <= ws_size || cg == 1) {
      g = cg; offWhist = oW; offTotal = oT; offBase = oBs; offA = oA; offB = oB;
      if (need <= ws_size) break;
    }
  }

  unsigned*  counts = (unsigned*)ws;
  long long* meta   = (long long*)(ws + 64);
  unsigned*  hist   = (unsigned*)(ws + offHist);
  unsigned*  whist  = (unsigned*)(ws + offWhist);
  unsigned*  total  = (unsigned*)(ws + offTotal);
  unsigned*  dbase  = (unsigned*)(ws + offBase);
  u64*       keysA  = (u64*)(ws + offA);
  u64*       keysB  = (u64*)(ws + offB);

  hipMemsetAsync(ws, 0, 512, stream);
  count_k<<<1024, 256, 0, stream>>>(coords, counts, N);
  prefix_k<<<1, 1, 0, stream>>>(counts, meta, bsz);
  flat2win_k<<<(N + 8 * GRP + 255) / 256, 256, 0, stream>>>(meta, dout);

  for (int g0 = 0; g0 < 6; g0 += g) {
    keygen_k<<<(N + 255) / 256, 256, 0, stream>>>(coords, keysA, meta, dout, N, g0, g, g0 == 0);
    u64* src = keysA; u64* dst = keysB;
    for (int p = 0; p < NPASS; p++) {
      int shift = KSHIFT + RBITS * p;
      int fin = (p == NPASS - 1);
      hist_k<<<dim3(B, g), BLOCK, 0, stream>>>(src, hist, whist, N, B, shift);
      scan_k<<<dim3(RADIX / 64, g), 64, 0, stream>>>(hist, total, B);
      base_k<<<g, 64, 0, stream>>>(total, dbase);
      scatter_k<<<dim3(B, g), BLOCK, 0, stream>>>(src, dst, hist, whist, dbase, N, B, shift, fin,
                                                  dout, meta, g0);
      u64* tmp = src; src = dst; dst = tmp;
    }
  }
}

// Round 4
// 484.466 us; speedup vs baseline: 1.6471x; 1.0448x over previous
//
#include <hip/hip_runtime.h>
#include <type_traits>

typedef unsigned long long u64;
typedef unsigned int u32;

#define BLOCK     256           // 4 waves
#define WAVES     4
#define TILE      4096          // items per hist/scatter block
#define SUBT      1024          // items per wave (contiguous, stability)
#define CHUNKS    16            // SUBT/64
#define KSHIFT    21
#define KBIAS     (1LL << 21)   // min key -1,787,119 > -2^21; max < 2^33
#define KMASK     ((1u << 21) - 1)
#define GRP       128

// Pass plan (33 key bits = 8+8+9+8, LSD):
//  p1: u64, radix 256, shift 21  (key bits [0,8))
//  p2: u64, radix 256, shift 29  (key bits [8,16))
//  p3: u64 -> u32, radix 512, shift 37 (key bits [16,25)); out = ((k>>46)<<21)|idx
//  p4: u32, radix 256, shift 21  (key bits [25,33)) -> int32 dout

__device__ __forceinline__ void hash3(long long x, long long y, long long z,
                                      long long boff, long long* v) {
  long long x1 = x >> 4, y1 = y >> 4, z1 = z >> 3;
  long long x2 = x & 15, y2 = y & 15, z2 = z & 7;
  long long sx  = 1 - 2*(x1 & 1), sy  = 1 - 2*(y1 & 1), sz  = 1 - 2*(z1 & 1);
  long long s2x = 1 - 2*(x2 & 1), s2y = 1 - 2*(y2 & 1), s2z = 1 - 2*(z2 & 1);
  v[0] = (99*y1 + 9801*z1 + sy*x1)*55296 + sy*(48*x2 + 2304*z2 + s2x*y2) + boff;
  v[1] = (99*z1 + 2673*x1 + sz*y1)*55296 + sz*(24*y2 + 1152*x2 + s2y*z2) + boff;
  v[2] = (27*x1 + 2673*y1 + sx*z1)*55296 + sx*(48*z2 + 1152*y2 + s2z*x2) + boff;
}

__global__ void count_k(const int* __restrict__ coords, unsigned* __restrict__ counts, int N) {
  __shared__ unsigned c[8];
  if (threadIdx.x < 8) c[threadIdx.x] = 0;
  __syncthreads();
  for (int i = blockIdx.x*blockDim.x + threadIdx.x; i < N; i += gridDim.x*blockDim.x)
    atomicAdd(&c[coords[4*i] & 7], 1u);
  __syncthreads();
  if (threadIdx.x < 8) atomicAdd(&counts[threadIdx.x], c[threadIdx.x]);
}

__global__ void prefix_k(const unsigned* __restrict__ counts, long long* __restrict__ meta,
                         const int* __restrict__ bsz) {
  int NB = *bsz; if (NB > 8) NB = 8;
  long long run_bs = 0, run_bsp = 0;
  meta[0] = 0;
  for (int b = 0; b < NB; b++) {
    long long c  = (long long)counts[b];
    long long cp = (c + GRP - 1) / GRP * GRP;
    long long r  = c % GRP;
    meta[9 + b]  = run_bsp - run_bs;
    meta[17 + b] = r ? (run_bsp + cp - GRP + r) : 0x7fffffffffffffffLL;
    run_bs += c; run_bsp += cp;
    meta[b + 1] = run_bsp;
  }
  meta[25] = run_bsp;
  meta[26] = NB;
}

__global__ void flat2win_k(const long long* __restrict__ meta, int* __restrict__ dout) {
  long long p = (long long)blockIdx.x * blockDim.x + threadIdx.x;
  long long Np = meta[25];
  if (p >= Np) return;
  int NB = (int)meta[26];
  int b = 0;
  while (b < NB - 1 && meta[b + 1] <= p) b++;
  long long pad = (p >= meta[17 + b]) ? 1 : 0;
  dout[p] = (int)(p - GRP * pad - meta[9 + b]);
}

// fused keygen + pass-1 histogram (radix 256 of low 8 key bits) + win2flat aux
__global__ void __launch_bounds__(BLOCK) keygen_k(const int* __restrict__ coords,
                                                  u64* __restrict__ keys,
                                                  u32* __restrict__ hist,
                                                  const long long* __restrict__ meta,
                                                  int* __restrict__ dout,
                                                  int N, int B, int g0, int g, int doAux) {
  __shared__ u32 cnt[6 * 256];
  int b = blockIdx.x, tid = threadIdx.x;
  int nb = g * 256;
  for (int j = tid; j < nb; j += BLOCK) cnt[j] = 0;
  __syncthreads();
  long long Np = meta[25];
  for (int t = 0; t < CHUNKS; t++) {
    int i = b * TILE + t * BLOCK + tid;
    if (i < N) {
      int4 c4 = ((const int4*)coords)[i];
      long long boff = (long long)c4.x * 167772160LL;
      long long v[6];
      hash3(c4.y,     c4.z,     c4.w,     boff, v);
      hash3(c4.y + 8, c4.z + 8, c4.w + 4, boff, v + 3);
      #pragma unroll
      for (int s = 0; s < 6; s++) {
        if (s >= g0 && s < g0 + g) {
          u64 kb = (u64)(v[s] + KBIAS);
          keys[(size_t)(s - g0) * N + i] = (kb << KSHIFT) | (unsigned)i;
          atomicAdd(&cnt[(s - g0) * 256 + ((unsigned)kb & 255)], 1u);
        }
      }
      if (doAux) dout[Np + i] = (int)(i + meta[9 + c4.x]);
    }
  }
  __syncthreads();
  for (int j = tid; j < nb; j += BLOCK) {
    int s = j >> 8, d = j & 255;
    hist[((size_t)s * B + b) * 256 + d] = cnt[j];
  }
}

template<typename KT, int RADIXN, int SHIFT>
__global__ void __launch_bounds__(BLOCK) hist_k(const KT* __restrict__ src,
                                                u32* __restrict__ hist, int N, int B) {
  __shared__ u32 cnt[RADIXN];
  int s = blockIdx.y, b = blockIdx.x, tid = threadIdx.x;
  for (int j = tid; j < RADIXN; j += BLOCK) cnt[j] = 0;
  __syncthreads();
  const KT* in = src + (size_t)s * N;
  #pragma unroll 4
  for (int t = 0; t < CHUNKS; t++) {
    int i = b * TILE + t * BLOCK + tid;
    if (i < N) {
      unsigned d = (unsigned)(in[i] >> SHIFT) & (RADIXN - 1);
      atomicAdd(&cnt[d], 1u);
    }
  }
  __syncthreads();
  for (int j = tid; j < RADIXN; j += BLOCK) hist[((size_t)s * B + b) * RADIXN + j] = cnt[j];
}

// per-sort single block: in-place exclusive scan of per-block hists + digit-base scan
template<int RADIXN>
__global__ void __launch_bounds__(BLOCK) scan_k(u32* __restrict__ hist,
                                                u32* __restrict__ dbase, int B) {
  __shared__ u32 tot[RADIXN];
  int s = blockIdx.x, tid = threadIdx.x;
  for (int d = tid; d < RADIXN; d += BLOCK) {
    u32 run = 0; int b = 0;
    for (; b + 8 <= B; b += 8) {
      u32 v[8];
      #pragma unroll
      for (int j = 0; j < 8; j++) v[j] = hist[((size_t)s * B + b + j) * RADIXN + d];
      #pragma unroll
      for (int j = 0; j < 8; j++) { hist[((size_t)s * B + b + j) * RADIXN + d] = run; run += v[j]; }
    }
    for (; b < B; b++) {
      size_t x = ((size_t)s * B + b) * RADIXN + d;
      u32 v = hist[x]; hist[x] = run; run += v;
    }
    tot[d] = run;
  }
  __syncthreads();
  if (tid < 64) {
    u32 run = 0;
    #pragma unroll
    for (int c = 0; c < RADIXN / 64; c++) {
      u32 v = tot[c * 64 + tid], x = v;
      for (int off = 1; off < 64; off <<= 1) { u32 u = __shfl_up(x, off); if (tid >= off) x += u; }
      dbase[(size_t)s * 512 + c * 64 + tid] = run + x - v;
      run += __shfl(x, 63);
    }
  }
}

// register-stash scatter: keys + (digit,rank) kept in VGPRs, per-wave LDS
// counters recomputed locally (no whist), LDS-staged coalesced write-out.
// MODE 0: u64->u64   MODE 1: u64->u32 shrink   MODE 2: u32->int32 dout
template<int RB, int SHIFT, int MODE>
__global__ void __launch_bounds__(BLOCK) scatter_k(const void* __restrict__ srcv,
                                                   void* __restrict__ dstv,
                                                   const u32* __restrict__ hist,
                                                   const u32* __restrict__ dbase,
                                                   int N, int B,
                                                   int* __restrict__ dout,
                                                   const long long* __restrict__ meta, int g0) {
  constexpr int RADIXN = 1 << RB;
  constexpr int DPT = (RADIXN + BLOCK - 1) / BLOCK;
  using KT = typename std::conditional<MODE == 2, u32, u64>::type;
  __shared__ KT items[TILE];
  __shared__ u32 cnt[WAVES][RADIXN];
  __shared__ int exf[RADIXN];
  int s = blockIdx.y, b = blockIdx.x, tid = threadIdx.x;
  int wave = tid >> 6, lane = tid & 63;
  for (int j = tid; j < WAVES * RADIXN; j += BLOCK) ((u32*)cnt)[j] = 0;
  __syncthreads();

  const KT* in = (const KT*)srcv + (size_t)s * N;
  int subbase = b * TILE + wave * SUBT;
  KT k[CHUNKS];
  #pragma unroll
  for (int t = 0; t < CHUNKS; t++) k[t] = in[min(subbase + t * 64 + lane, N - 1)];

  u64 lt = (1ULL << lane) - 1;
  u32 pd[CHUNKS];
  #pragma unroll
  for (int t = 0; t < CHUNKS; t++) {
    int i = subbase + t * 64 + lane;
    bool valid = i < N;
    unsigned d = (unsigned)(k[t] >> SHIFT) & (RADIXN - 1);
    u64 m = __ballot(valid);
    #pragma unroll
    for (int bit = 0; bit < RB; bit++) {
      u64 bal = __ballot(valid && ((d >> bit) & 1));
      m &= ((d >> bit) & 1) ? bal : ~bal;
    }
    u64 below = m & lt;
    unsigned rank = (unsigned)__popcll(below);
    unsigned pbase = cnt[wave][d];              // lockstep: all read before leader writes
    pd[t] = d | ((pbase + rank) << RB);
    if (valid && below == 0) cnt[wave][d] = pbase + (unsigned)__popcll(m);
  }
  __syncthreads();

  // totals -> exf; save per-wave counts in registers
  u32 sc[DPT][3];
  #pragma unroll
  for (int q = 0; q < DPT; q++) {
    int d = q * BLOCK + tid;
    u32 a0 = cnt[0][d], a1 = cnt[1][d], a2 = cnt[2][d], a3 = cnt[3][d];
    sc[q][0] = a0; sc[q][1] = a1; sc[q][2] = a2;
    exf[d] = (int)(a0 + a1 + a2 + a3);
  }
  __syncthreads();
  if (tid < 64) {                               // wave0: exclusive scan of block totals
    u32 run = 0;
    #pragma unroll
    for (int c = 0; c < RADIXN / 64; c++) {
      int dd = c * 64 + tid;
      u32 v = (u32)exf[dd], x = v;
      for (int off = 1; off < 64; off <<= 1) { u32 u = __shfl_up(x, off); if (tid >= off) x += u; }
      exf[dd] = (int)(run + x - v);
      run += __shfl(x, 63);
    }
  }
  __syncthreads();
  const u32* hrow = hist + (size_t)(s * B + b) * RADIXN;
  const u32* brow = dbase + (size_t)s * 512;
  #pragma unroll
  for (int q = 0; q < DPT; q++) {
    int d = q * BLOCK + tid;
    int e = exf[d];
    u32 gb = hrow[d] + brow[d];
    cnt[0][d] = e;
    cnt[1][d] = e + sc[q][0];
    cnt[2][d] = e + sc[q][0] + sc[q][1];
    cnt[3][d] = e + sc[q][0] + sc[q][1] + sc[q][2];
    exf[d] = (int)gb - e;                       // global = exf[d] + local slot
  }
  __syncthreads();

  #pragma unroll
  for (int t = 0; t < CHUNKS; t++) {
    int i = subbase + t * 64 + lane;
    if (i < N) {
      unsigned d = pd[t] & (RADIXN - 1);
      unsigned lr = pd[t] >> RB;
      items[cnt[wave][d] + lr] = k[t];
    }
  }
  __syncthreads();

  int validCount = N - b * TILE; if (validCount > TILE) validCount = TILE;
  long long obase = 0;
  if (MODE == 2) obase = meta[25] + (long long)N * (1 + g0 + s);
  u64* out64 = (u64*)dstv + (size_t)s * N;
  u32* out32 = (u32*)dstv + (size_t)s * N;
  #pragma unroll 4
  for (int t = 0; t < CHUNKS; t++) {
    int j = t * BLOCK + tid;
    if (j < validCount) {
      KT kk = items[j];
      unsigned d = (unsigned)(kk >> SHIFT) & (RADIXN - 1);
      int gpos = exf[d] + j;
      if constexpr (MODE == 0)      out64[gpos] = kk;
      else if constexpr (MODE == 1) out32[gpos] = (u32)(((kk >> 46) << 21) | (kk & KMASK));
      else                          dout[obase + gpos] = (int)(kk & KMASK);
    }
  }
}

extern "C" void kernel_launch(void* const* d_in, const int* in_sizes, int n_in,
                              void* d_out, int out_size, void* d_ws, size_t ws_size,
                              hipStream_t stream) {
  const int* coords = (const int*)d_in[0];
  const int* bsz    = (const int*)d_in[1];
  int N = in_sizes[0] / 4;
  int* dout = (int*)d_out;
  char* ws = (char*)d_ws;
  int B = (N + TILE - 1) / TILE;

  auto align256 = [](size_t x) { return (x + 255) & ~(size_t)255; };

  int g = 1;
  size_t offHist = 512, offBase = 0, offA = 0, offB = 0;
  const int cands[4] = {6, 3, 2, 1};
  for (int ci = 0; ci < 4; ci++) {
    int cg = cands[ci];
    size_t oBs = offHist + (size_t)cg * B * 512 * 4;
    size_t oA = align256(oBs + (size_t)cg * 512 * 4);
    size_t oB = oA + (size_t)cg * N * 8;
    size_t need = oB + (size_t)cg * N * 8;
    if (need <= ws_size || cg == 1) {
      g = cg; offBase = oBs; offA = oA; offB = oB;
      if (need <= ws_size) break;
    }
  }

  unsigned*  counts = (unsigned*)ws;
  long long* meta   = (long long*)(ws + 64);
  u32*       hist   = (u32*)(ws + offHist);
  u32*       dbase  = (u32*)(ws + offBase);
  u64*       keysA  = (u64*)(ws + offA);
  u64*       keysB  = (u64*)(ws + offB);

  hipMemsetAsync(ws, 0, 512, stream);
  count_k<<<1024, 256, 0, stream>>>(coords, counts, N);
  prefix_k<<<1, 1, 0, stream>>>(counts, meta, bsz);
  flat2win_k<<<(N + 8 * GRP + 255) / 256, 256, 0, stream>>>(meta, dout);

  for (int g0 = 0; g0 < 6; g0 += g) {
    keygen_k<<<B, BLOCK, 0, stream>>>(coords, keysA, hist, meta, dout, N, B, g0, g, g0 == 0);
    // pass 1: u64 radix 256 @21, A -> B
    scan_k<256><<<g, BLOCK, 0, stream>>>(hist, dbase, B);
    scatter_k<8, 21, 0><<<dim3(B, g), BLOCK, 0, stream>>>(keysA, keysB, hist, dbase, N, B,
                                                          dout, meta, g0);
    // pass 2: u64 radix 256 @29, B -> A
    hist_k<u64, 256, 29><<<dim3(B, g), BLOCK, 0, stream>>>(keysB, hist, N, B);
    scan_k<256><<<g, BLOCK, 0, stream>>>(hist, dbase, B);
    scatter_k<8, 29, 0><<<dim3(B, g), BLOCK, 0, stream>>>(keysB, keysA, hist, dbase, N, B,
                                                          dout, meta, g0);
    // pass 3: u64 radix 512 @37, A -> B (u32 shrink)
    hist_k<u64, 512, 37><<<dim3(B, g), BLOCK, 0, stream>>>(keysA, hist, N, B);
    scan_k<512><<<g, BLOCK, 0, stream>>>(hist, dbase, B);
    scatter_k<9, 37, 1><<<dim3(B, g), BLOCK, 0, stream>>>(keysA, keysB, hist, dbase, N, B,
                                                          dout, meta, g0);
    // pass 4: u32 radix 256 @21, B(u32) -> dout
    hist_k<u32, 256, 21><<<dim3(B, g), BLOCK, 0, stream>>>((const u32*)keysB, hist, N, B);
    scan_k<256><<<g, BLOCK, 0, stream>>>(hist, dbase, B);
    scatter_k<8, 21, 2><<<dim3(B, g), BLOCK, 0, stream>>>(keysB, keysA, hist, dbase, N, B,
                                                          dout, meta, g0);
  }
}